// Round 8
// baseline (105.039 us; speedup 1.0000x reference)
//
#include <hip/hip_runtime.h>

// Problem constants
#define IN_DIM   512
#define OUT_DIM  512
#define KDEG     3
#define BATCH    256
#define NB       19                 // spline basis count per input dim
#define NG       23                 // grid points per input dim
#define KAUG     20                 // 19 spline slots + 1 base(silu) slot
#define KTOT     (IN_DIM * KAUG)    // 10240

typedef short  bf16x8 __attribute__((ext_vector_type(8)));   // 8 bf16 = 4 VGPRs
typedef float  f32x4  __attribute__((ext_vector_type(4)));

// round-to-nearest-even fp32 -> bf16
__device__ __forceinline__ unsigned short f2bf(float f) {
    union { float f; unsigned int u; } v; v.f = f;
    unsigned int r = (v.u + 0x7FFF + ((v.u >> 16) & 1)) >> 16;
    return (unsigned short)r;
}

// ---------------------------------------------------------------------------
// Kernel 1: augmented A (BATCH x KTOT), bf16, k-contiguous.
//   A[b][i*20+g] = Bspline_g(x[b,i]),  A[b][i*20+19] = silu(x[b,i])
// ---------------------------------------------------------------------------
__global__ void build_A(const float* __restrict__ X,
                        const float* __restrict__ G,
                        unsigned short* __restrict__ A) {
    int t = blockIdx.x * blockDim.x + threadIdx.x;
    if (t >= BATCH * IN_DIM) return;
    int b = t / IN_DIM;
    int i = t - b * IN_DIM;

    float x = X[t];

    float gr[NG];
    const float* g = G + i * NG;
#pragma unroll
    for (int j = 0; j < NG; j++) gr[j] = g[j];

    float B[NG - 1];
#pragma unroll
    for (int j = 0; j < NG - 1; j++)
        B[j] = (x >= gr[j] && x < gr[j + 1]) ? 1.0f : 0.0f;

#pragma unroll
    for (int kk = 1; kk <= KDEG; kk++) {
#pragma unroll
        for (int j = 0; j < NG - 1 - kk; j++) {
            float d1 = gr[j + kk] - gr[j];
            float d2 = gr[j + kk + 1] - gr[j + 1];
            B[j] = (x - gr[j]) / d1 * B[j] +
                   (gr[j + kk + 1] - x) / d2 * B[j + 1];
        }
    }

    unsigned short v[KAUG];
#pragma unroll
    for (int j = 0; j < NB; j++) v[j] = f2bf(B[j]);
    v[NB] = f2bf(x / (1.0f + __expf(-x)));   // silu

    unsigned int* dst = (unsigned int*)(A + (size_t)b * KTOT + i * KAUG);
    const unsigned int* src = (const unsigned int*)v;
#pragma unroll
    for (int d = 0; d < KAUG / 2; d++) dst[d] = src[d];
}

// ---------------------------------------------------------------------------
// Kernel 2 (fused W-build + split-K GEMM).  R6 structure exactly; the ONLY
// change: epilogue writes fp32 atomicAdd directly into out (no P buffer).
// Grid = (16 o-blocks, 1, 32 k-splits) = 512 blocks, 512 threads = 8 waves;
// BM=256 (wave w owns rows [32w,32w+32)), BN=32, ICH=16 -> KCH=320.
// ---------------------------------------------------------------------------
#define BN     32
#define SPLITS 32
#define ICH    16                  // i's per block
#define KCH    (ICH * KAUG)        // 320
#define LDS_K  (KCH + 8)           // 328 elems -> row stride 656B

__global__ __launch_bounds__(512, 4) void gemm_fused(
        const unsigned short* __restrict__ A,
        const float* __restrict__ coef,
        const float* __restrict__ scale_sp,
        const float* __restrict__ mask,
        float* __restrict__ out) {
    __shared__ __align__(16) unsigned short Bs[BN * LDS_K];   // 20992 B
    __shared__ float smt[ICH * 32];                           // 2048 B

    int tid = threadIdx.x;
    int o0 = blockIdx.x * BN;
    int i0 = blockIdx.z * ICH;
    int kbase = blockIdx.z * KCH;

    // ---- fill pass 1: scale*mask table + silu-slot weights (coalesced) ----
    {
        int o  = tid & 31;         // lanes sweep o
        int di = tid >> 5;         // 0..15
        int io = (i0 + di) * OUT_DIM + (o0 + o);
        float m  = mask[io];
        float sm = scale_sp[io] * m;
        smt[di * 32 + o] = sm;
        Bs[o * LDS_K + di * KAUG + NB] = f2bf(m);   // silu-slot weight
    }
    __syncthreads();

    // ---- fill pass 2: coalesced float4 coef -> Bs -------------------------
    for (int p = tid; p < ICH * 152; p += 512) {
        int di  = p / 152;
        int rem = p - di * 152;
        f32x4 v = *(const f32x4*)(coef
              + ((size_t)(i0 + di) * OUT_DIM + o0) * NB + rem * 4);
#pragma unroll
        for (int e = 0; e < 4; e++) {
            int l = rem * 4 + e;          // 0..607
            int o_loc = l / 19;
            int g = l - o_loc * 19;
            Bs[o_loc * LDS_K + di * KAUG + g] = f2bf(v[e] * smt[di * 32 + o_loc]);
        }
    }
    __syncthreads();

    // ---- compute phase: barrier-free unrolled K-loop ----------------------
    int lane = tid & 63;
    int w    = tid >> 6;           // wave 0..7, owns m-strip [32w, 32w+32)
    int quad = lane >> 4;
    int lr   = lane & 15;

    f32x4 acc[2][2];
#pragma unroll
    for (int i = 0; i < 2; i++)
#pragma unroll
        for (int j = 0; j < 2; j++) acc[i][j] = (f32x4)0.0f;

    const unsigned short* a0 = A + (size_t)(w * 32 + lr)      * KTOT + kbase + quad * 8;
    const unsigned short* a1 = A + (size_t)(w * 32 + 16 + lr) * KTOT + kbase + quad * 8;
    const unsigned short* b0 = &Bs[(size_t)lr        * LDS_K + quad * 8];
    const unsigned short* b1 = &Bs[(size_t)(16 + lr) * LDS_K + quad * 8];

#pragma unroll
    for (int kk = 0; kk < KCH; kk += 32) {
        bf16x8 af0 = *(const bf16x8*)(a0 + kk);
        bf16x8 af1 = *(const bf16x8*)(a1 + kk);
        bf16x8 bf0 = *(const bf16x8*)(b0 + kk);
        bf16x8 bf1 = *(const bf16x8*)(b1 + kk);
        acc[0][0] = __builtin_amdgcn_mfma_f32_16x16x32_bf16(af0, bf0, acc[0][0], 0, 0, 0);
        acc[0][1] = __builtin_amdgcn_mfma_f32_16x16x32_bf16(af0, bf1, acc[0][1], 0, 0, 0);
        acc[1][0] = __builtin_amdgcn_mfma_f32_16x16x32_bf16(af1, bf0, acc[1][0], 0, 0, 0);
        acc[1][1] = __builtin_amdgcn_mfma_f32_16x16x32_bf16(af1, bf1, acc[1][1], 0, 0, 0);
    }

    // ---- epilogue: C/D layout col=lane&15, row=quad*4+reg; atomics to out -
#pragma unroll
    for (int mt = 0; mt < 2; mt++) {
#pragma unroll
        for (int nt = 0; nt < 2; nt++) {
            int col = o0 + nt * 16 + lr;
            int rb  = w * 32 + mt * 16 + quad * 4;
#pragma unroll
            for (int r = 0; r < 4; r++)
                atomicAdd(&out[(size_t)(rb + r) * OUT_DIM + col], acc[mt][nt][r]);
        }
    }
}

// ---------------------------------------------------------------------------
extern "C" void kernel_launch(void* const* d_in, const int* in_sizes, int n_in,
                              void* d_out, int out_size, void* d_ws, size_t ws_size,
                              hipStream_t stream) {
    const float* x        = (const float*)d_in[0];   // (256, 512)
    const float* grid     = (const float*)d_in[1];   // (512, 23)
    const float* coef     = (const float*)d_in[2];   // (512, 512, 19)
    const float* scale_sp = (const float*)d_in[3];   // (512, 512)
    const float* mask     = (const float*)d_in[4];   // (512, 512)
    float* out = (float*)d_out;                      // (256, 512)

    unsigned short* A = (unsigned short*)d_ws;       // 5.24 MB

    hipMemsetAsync(d_out, 0, (size_t)out_size * sizeof(float), stream);

    build_A<<<dim3((BATCH * IN_DIM + 255) / 256), dim3(256), 0, stream>>>(x, grid, A);

    gemm_fused<<<dim3(OUT_DIM / BN, 1, SPLITS), dim3(512), 0, stream>>>(
        A, coef, scale_sp, mask, out);
}

// Round 9
// 99.044 us; speedup vs baseline: 1.0605x; 1.0605x over previous
//
#include <hip/hip_runtime.h>

// Problem constants
#define IN_DIM   512
#define OUT_DIM  512
#define KDEG     3
#define BATCH    256
#define NB       19                 // spline basis count per input dim
#define NG       23                 // grid points per input dim
#define KAUG     20                 // 19 spline slots + 1 base(silu) slot
#define KTOT     (IN_DIM * KAUG)    // 10240

typedef short  bf16x8 __attribute__((ext_vector_type(8)));   // 8 bf16 = 4 VGPRs
typedef float  f32x4  __attribute__((ext_vector_type(4)));

// round-to-nearest-even fp32 -> bf16
__device__ __forceinline__ unsigned short f2bf(float f) {
    union { float f; unsigned int u; } v; v.f = f;
    unsigned int r = (v.u + 0x7FFF + ((v.u >> 16) & 1)) >> 16;
    return (unsigned short)r;
}

__device__ __forceinline__ float bf2f(unsigned short h) {
    union { unsigned int u; float f; } v;
    v.u = ((unsigned int)h) << 16;
    return v.f;
}

// ---------------------------------------------------------------------------
// Kernel 1: augmented A (BATCH x KTOT), bf16, k-contiguous.  (R4 version)
// ---------------------------------------------------------------------------
__global__ void build_A(const float* __restrict__ X,
                        const float* __restrict__ G,
                        unsigned short* __restrict__ A) {
    int t = blockIdx.x * blockDim.x + threadIdx.x;
    if (t >= BATCH * IN_DIM) return;
    int b = t / IN_DIM;
    int i = t - b * IN_DIM;

    float x = X[t];

    float gr[NG];
    const float* g = G + i * NG;
#pragma unroll
    for (int j = 0; j < NG; j++) gr[j] = g[j];

    float B[NG - 1];
#pragma unroll
    for (int j = 0; j < NG - 1; j++)
        B[j] = (x >= gr[j] && x < gr[j + 1]) ? 1.0f : 0.0f;

#pragma unroll
    for (int kk = 1; kk <= KDEG; kk++) {
#pragma unroll
        for (int j = 0; j < NG - 1 - kk; j++) {
            float d1 = gr[j + kk] - gr[j];
            float d2 = gr[j + kk + 1] - gr[j + 1];
            B[j] = (x - gr[j]) / d1 * B[j] +
                   (gr[j + kk + 1] - x) / d2 * B[j + 1];
        }
    }

    unsigned short v[KAUG];
#pragma unroll
    for (int j = 0; j < NB; j++) v[j] = f2bf(B[j]);
    v[NB] = f2bf(x / (1.0f + __expf(-x)));   // silu

    unsigned int* dst = (unsigned int*)(A + (size_t)b * KTOT + i * KAUG);
    const unsigned int* src = (const unsigned int*)v;
#pragma unroll
    for (int d = 0; d < KAUG / 2; d++) dst[d] = src[d];
}

// ---------------------------------------------------------------------------
// Kernel 2 (fused W-build + split-K GEMM -> bf16 partials).  Exactly R4's
// structure; ONLY change: P stored as bf16 (halves partial-buffer traffic).
// Grid = (16 o-blocks, 1, 32 k-splits) = 512 blocks, 512 threads = 8 waves;
// BM=256 (wave w owns rows [32w,32w+32)), BN=32, ICH=16 -> KCH=320.
// ---------------------------------------------------------------------------
#define BN     32
#define SPLITS 32
#define ICH    16                  // i's per block
#define KCH    (ICH * KAUG)        // 320
#define LDS_K  (KCH + 8)           // 328 elems -> row stride 656B

__global__ __launch_bounds__(512, 4) void gemm_fused(
        const unsigned short* __restrict__ A,
        const float* __restrict__ coef,
        const float* __restrict__ scale_sp,
        const float* __restrict__ mask,
        unsigned short* __restrict__ P) {
    __shared__ __align__(16) unsigned short Bs[BN * LDS_K];   // 20992 B

    int tid = threadIdx.x;
    int o0 = blockIdx.x * BN;
    int i0 = blockIdx.z * ICH;
    int kbase = blockIdx.z * KCH;

    // ---- fill phase: 16i x 32o = 512 (i,o) pairs, 1 per thread (R4) -------
    {
        int o  = tid & 31;         // lanes sweep o -> coalesced mask/scale
        int di = tid >> 5;         // 0..15
        int io = (i0 + di) * OUT_DIM + (o0 + o);
        float m  = mask[io];
        float sm = scale_sp[io] * m;
        const float* c = coef + (size_t)io * NB;

        __align__(8) unsigned short v[KAUG];
#pragma unroll
        for (int g = 0; g < NB; g++) v[g] = f2bf(c[g] * sm);
        v[NB] = f2bf(m);           // silu-slot weight

        unsigned long long* dst =
            (unsigned long long*)((char*)Bs + (size_t)o * (LDS_K * 2) + di * (KAUG * 2));
        const unsigned long long* src = (const unsigned long long*)v;
#pragma unroll
        for (int d = 0; d < 5; d++) dst[d] = src[d];
    }
    __syncthreads();               // the ONLY barrier

    // ---- compute phase: barrier-free unrolled K-loop ----------------------
    int lane = tid & 63;
    int w    = tid >> 6;           // wave 0..7, owns m-strip [32w, 32w+32)
    int quad = lane >> 4;
    int lr   = lane & 15;

    f32x4 acc[2][2];
#pragma unroll
    for (int i = 0; i < 2; i++)
#pragma unroll
        for (int j = 0; j < 2; j++) acc[i][j] = (f32x4)0.0f;

    const unsigned short* a0 = A + (size_t)(w * 32 + lr)      * KTOT + kbase + quad * 8;
    const unsigned short* a1 = A + (size_t)(w * 32 + 16 + lr) * KTOT + kbase + quad * 8;
    const unsigned short* b0 = &Bs[(size_t)lr        * LDS_K + quad * 8];
    const unsigned short* b1 = &Bs[(size_t)(16 + lr) * LDS_K + quad * 8];

#pragma unroll
    for (int kk = 0; kk < KCH; kk += 32) {
        bf16x8 af0 = *(const bf16x8*)(a0 + kk);
        bf16x8 af1 = *(const bf16x8*)(a1 + kk);
        bf16x8 bf0 = *(const bf16x8*)(b0 + kk);
        bf16x8 bf1 = *(const bf16x8*)(b1 + kk);
        acc[0][0] = __builtin_amdgcn_mfma_f32_16x16x32_bf16(af0, bf0, acc[0][0], 0, 0, 0);
        acc[0][1] = __builtin_amdgcn_mfma_f32_16x16x32_bf16(af0, bf1, acc[0][1], 0, 0, 0);
        acc[1][0] = __builtin_amdgcn_mfma_f32_16x16x32_bf16(af1, bf0, acc[1][0], 0, 0, 0);
        acc[1][1] = __builtin_amdgcn_mfma_f32_16x16x32_bf16(af1, bf1, acc[1][1], 0, 0, 0);
    }

    // ---- epilogue: bf16 stores into per-split partial buffer --------------
    // C/D layout: col=lane&15, row=quad*4+reg
    unsigned short* Pz = P + (size_t)blockIdx.z * BATCH * OUT_DIM;
#pragma unroll
    for (int mt = 0; mt < 2; mt++) {
#pragma unroll
        for (int nt = 0; nt < 2; nt++) {
            int col = o0 + nt * 16 + lr;
            int rb  = w * 32 + mt * 16 + quad * 4;
#pragma unroll
            for (int r = 0; r < 4; r++)
                Pz[(size_t)(rb + r) * OUT_DIM + col] = f2bf(acc[mt][nt][r]);
        }
    }
}

// ---------------------------------------------------------------------------
// Kernel 3: reduce bf16 partials: out[e] = sum_z P[z][e].
// Each thread handles 8 outputs (one 16B bf16x8 per split). 64 blocks x 256.
// ---------------------------------------------------------------------------
__global__ __launch_bounds__(256) void reduce_out(const unsigned short* __restrict__ P,
                                                  float* __restrict__ out) {
    int e8 = blockIdx.x * blockDim.x + threadIdx.x;   // 0 .. 16383
    float s[8] = {};
#pragma unroll
    for (int zz = 0; zz < SPLITS; zz++) {
        bf16x8 v = *(const bf16x8*)(P + (size_t)zz * BATCH * OUT_DIM + (size_t)e8 * 8);
#pragma unroll
        for (int j = 0; j < 8; j++)
            s[j] += bf2f((unsigned short)v[j]);
    }
    f32x4* o4 = (f32x4*)(out + (size_t)e8 * 8);
    o4[0] = *(f32x4*)&s[0];
    o4[1] = *(f32x4*)&s[4];
}

// ---------------------------------------------------------------------------
extern "C" void kernel_launch(void* const* d_in, const int* in_sizes, int n_in,
                              void* d_out, int out_size, void* d_ws, size_t ws_size,
                              hipStream_t stream) {
    const float* x        = (const float*)d_in[0];   // (256, 512)
    const float* grid     = (const float*)d_in[1];   // (512, 23)
    const float* coef     = (const float*)d_in[2];   // (512, 512, 19)
    const float* scale_sp = (const float*)d_in[3];   // (512, 512)
    const float* mask     = (const float*)d_in[4];   // (512, 512)
    float* out = (float*)d_out;                      // (256, 512)

    unsigned short* A = (unsigned short*)d_ws;                              // 5.24 MB
    unsigned short* P = (unsigned short*)((char*)d_ws + (size_t)BATCH * KTOT * 2); // 8.39 MB

    build_A<<<dim3((BATCH * IN_DIM + 255) / 256), dim3(256), 0, stream>>>(x, grid, A);

    gemm_fused<<<dim3(OUT_DIM / BN, 1, SPLITS), dim3(512), 0, stream>>>(
        A, coef, scale_sp, mask, P);

    reduce_out<<<dim3(BATCH * OUT_DIM / 8 / 256), dim3(256), 0, stream>>>(P, out);
}